// Round 21
// baseline (225.853 us; speedup 1.0000x reference)
//
#include <hip/hip_runtime.h>
#include <hip/hip_bf16.h>

#define BATCH 32768

typedef unsigned short u16;
typedef unsigned int u32;
typedef __attribute__((ext_vector_type(8))) short bf16x8;
typedef __attribute__((ext_vector_type(4))) float f32x4;

__device__ __forceinline__ float bf2f(u16 u) {
    union { u32 u; float f; } c; c.u = ((u32)u) << 16; return c.f;
}
// HW bf16 conversion (RNE), gfx950 v_cvt_pk_bf16_f32: 1 VALU for 2 floats.
__device__ __forceinline__ u16 f2bf(float f) {
    u32 r;
    asm("v_cvt_pk_bf16_f32 %0, %1, %1" : "=v"(r) : "v"(f));
    return (u16)r;
}
__device__ __forceinline__ u32 f2bf2(float lo, float hi) {  // [bf(lo) | bf(hi)<<16]
    u32 r;
    asm("v_cvt_pk_bf16_f32 %0, %1, %2" : "=v"(r) : "v"(lo), "v"(hi));
    return r;
}
__device__ __forceinline__ u16 i2bf(int v) {   // exact for small non-neg ints
    union { float f; u32 u; } c; c.f = (float)v;
    return (u16)(c.u >> 16);
}

// ---------------- K0: weight prep (R9 layouts) ---------------------------
__global__ __launch_bounds__(256) void k0_prep(const float* __restrict__ pw,
        const float* __restrict__ w2, const float* __restrict__ w3,
        const float* __restrict__ h2w, const float* __restrict__ h1w,
        const float* __restrict__ w1,
        u16* __restrict__ pwT, u16* __restrict__ w2r, u16* __restrict__ w3r,
        u16* __restrict__ h2hi, u16* __restrict__ h2lo,
        u16* __restrict__ h1hi, u16* __restrict__ h1lo,
        u16* __restrict__ w1hi, u16* __restrict__ w1lo) {
    int idx = blockIdx.x * 256 + threadIdx.x;
    if (idx < 38912) {
        int j = idx / 608, kk = idx - j * 608;
        float v = 0.f;
        if (kk < 576) {
            int p = kk >> 6, oc = kk & 63;
            v = pw[j * 578 + oc * 9 + p];
        } else if (kk < 578) {
            v = pw[j * 578 + kk];
        }
        pwT[idx] = f2bf(v);
    } else if (idx < 40960) {
        int i = idx - 38912;
        int oc = i >> 6, rem = i & 63, tap = rem >> 4, ic = rem & 15;
        w2r[i] = f2bf(w2[oc * 64 + ic * 4 + tap]);
    } else if (idx < 49152) {
        int i = idx - 40960;
        int oc = i >> 7, rem = i & 127, tap = rem >> 5, ic = rem & 31;
        w3r[i] = f2bf(w3[oc * 128 + ic * 4 + tap]);
    } else if (idx < 65536) {
        int i = idx - 49152;
        float v = h2w[i];
        u16 hi = f2bf(v);
        h2hi[i] = hi;
        h2lo[i] = f2bf(v - bf2f(hi));
    } else if (idx < 86016) {
        int i = idx - 65536;
        int j = i / 160, k = i - j * 160;
        float v = (k < 132) ? h1w[j * 132 + k] : 0.f;
        u16 hi = f2bf(v);
        h1hi[i] = hi;
        h1lo[i] = f2bf(v - bf2f(hi));
    } else if (idx < 86528) {
        int i = idx - 86016;               // [oc16][k32], k = ky*8+kx*4+c
        int oc = i >> 5, k = i & 31;
        int ky = k >> 3, kx = (k >> 2) & 1, c = k & 3;
        float v = (ky < 2 && c < 3) ? w1[oc * 12 + c * 4 + ky * 2 + kx] : 0.f;
        u16 hi = f2bf(v);
        w1hi[i] = hi;
        w1lo[i] = f2bf(v - bf2f(hi));
    }
}

// ---------------- KALL: whole network, 1 block = 16 pairs, 512 threads ---
// R20 = R19 (best: kall ~117.6 us) minus the mid-phase-D barrier:
// comb stride 168->132 u16 (2-way bank alias = free) and relocated to
// [0,4224); featL shifted +256 u16 to [4352,23040) -> comb writes are
// DISJOINT from featL reads -> D's epilogue no longer needs the inner
// __syncthreads. E's s=4 over-reads (k>=132) hit stale finite bf16
// multiplied by h1hi/h1lo's zero padding -> exact zeros (same mechanism
// R19 already relied on for comb cols 132-167).
__global__ __launch_bounds__(512, 4) void kall(const int* __restrict__ frame,
        const u16* __restrict__ w1hi, const u16* __restrict__ w1lo,
        const float* __restrict__ b1,
        const u16* __restrict__ w2r, const float* __restrict__ b2,
        const u16* __restrict__ w3r, const float* __restrict__ b3,
        const int* __restrict__ ccol, const int* __restrict__ cobj,
        const u16* __restrict__ pwT, const float* __restrict__ pb,
        const u16* __restrict__ h1hi, const u16* __restrict__ h1lo,
        const float* __restrict__ h1b,
        const float* __restrict__ lng, const float* __restrict__ lnb,
        const u16* __restrict__ h2hi, const u16* __restrict__ h2lo,
        const float* __restrict__ h2b,
        const float* __restrict__ h3w, const float* __restrict__ h3b,
        float* __restrict__ out) {
    __shared__ u16 lds[23040];     // 46080 B
    __shared__ float4 fdirL[32];   // 512 B
    u16* p2L    = lds;             // [0,4096)      32 x 128
    u16* p1L    = lds + 4096;      // [4096,12288)  32 x 256
    u16* frL4   = lds + 12288;     // [12288,22784) 32 x 328 (4-ch, both h)
    u16* featL  = lds + 4352;      // [4352,23040)  32 x 584 (overlay after B)
    u16* combHi = lds;             // [0,2112)      16 x 132
    u16* combLo = lds + 2112;      // [2112,4224)
    float* hL   = (float*)(lds + 5376);  // [5376,9600) 16 x 132 f32
    u16* hLhi   = lds + 9600;      // [9600,12288)  16 x 168
    u16* hLlo   = lds + 12288;     // [12288,14976)

    int t = threadIdx.x;
    int l = t & 63;
    int wv = t >> 6;               // 0..7
    int col = l & 15;
    int kg = l >> 4;
    int wq = wv & 3, wh = wv >> 2;
    int b0 = blockIdx.x * 16;

    // halo-only zero (rows 0/8, cols 0/8, pad: 33 uint2/elem, disjoint from
    // loader interior writes -> NO barrier between zero and load)
    #pragma unroll
    for (int i = 0; i < 3; ++i) {
        int idx = i * 512 + t;
        if (idx < 1056) {
            int le = idx / 33, h = idx - le * 33;
            int off;
            if (h < 9) off = h * 4;                       // row 0
            else if (h < 18) off = 288 + (h - 9) * 4;     // row 8
            else if (h < 25) off = (h - 17) * 36;         // col 0, rows 1-7
            else if (h < 32) off = (h - 24) * 36 + 32;    // col 8, rows 1-7
            else off = 324;                               // elem pad
            *(uint2*)(frL4 + le * 328 + off) = make_uint2(0u, 0u);
        }
    }
    // cell loader: 1 thread = 1 pixel (3 ints -> packed 4ch uint2)
    #pragma unroll
    for (int i = 0; i < 4; ++i) {
        int c = i * 512 + t;
        if (c < 1568) {
            int le = c / 49, rem = c - le * 49;
            int y = rem / 7, x = rem - y * 7;
            const int* fp = frame
                + ((size_t)b0 + (size_t)(le & 15) + (size_t)(le >> 4) * BATCH) * 147
                + rem * 3;
            int v0 = fp[0], v1 = fp[1], v2 = fp[2];
            uint2 st;
            st.x = (u32)i2bf(v0) | ((u32)i2bf(v1) << 16);
            st.y = (u32)i2bf(v2);                          // ch3 = 0
            *(uint2*)(frL4 + le * 328 + (y + 1) * 36 + (x + 1) * 4) = st;
        }
    }
    __syncthreads();

    // ---- phase A+B fused: conv1+pool -> (same-wave) conv2+pool ----------
    {
        // -- A: conv1+relu+pool (2 MFMA hi/lo, kg<2 loads), wave-own elems --
        bf16x8 c1hi = *(const bf16x8*)(w1hi + col * 32 + kg * 8);
        bf16x8 c1lo = *(const bf16x8*)(w1lo + col * 32 + kg * 8);
        float c1b = b1[col];
        bool wr1 = (kg < 2);
        #pragma unroll
        for (int q = 0; q < 4; ++q) {
            int le = wh * 16 + wq * 4 + q;
            const u16* eb = frL4 + le * 328;
            u16* op = p1L + le * 256;
            #pragma unroll
            for (int mt = 0; mt < 4; ++mt) {
                int posA = mt * 16 + col;
                int oy = posA >> 3, ox = posA & 7;
                bf16x8 a;
                if (kg < 2) {      // K-slice kg = row ky; 2 pixels x 4ch
                    const u16* ap = eb + (oy + kg) * 36 + ox * 4;
                    union { uint2 d[2]; bf16x8 v; } uu;
                    uu.d[0] = *(const uint2*)ap;
                    uu.d[1] = *(const uint2*)(ap + 4);
                    a = uu.v;
                } else {
                    #pragma unroll
                    for (int j = 0; j < 8; ++j) a[j] = 0;
                }
                f32x4 acc = {0.f, 0.f, 0.f, 0.f};
                acc = __builtin_amdgcn_mfma_f32_16x16x32_bf16(a, c1hi, acc, 0, 0, 0);
                acc = __builtin_amdgcn_mfma_f32_16x16x32_bf16(a, c1lo, acc, 0, 0, 0);
                float x0 = fmaxf(acc[0] + c1b, 0.f);
                float x1 = fmaxf(acc[1] + c1b, 0.f);
                float x2 = fmaxf(acc[2] + c1b, 0.f);
                float x3 = fmaxf(acc[3] + c1b, 0.f);
                float y0 = fmaxf(x0, x1);
                float y1 = fmaxf(x2, x3);
                float m0 = fmaxf(y0, __shfl_xor(y0, 32, 64));
                float m1 = fmaxf(y1, __shfl_xor(y1, 32, 64));
                if (wr1) {
                    op[(mt * 4 + kg * 2 + 0) * 16 + col] = f2bf(m0);
                    op[(mt * 4 + kg * 2 + 1) * 16 + col] = f2bf(m1);
                }
            }
        }
        // dir/pos scan (16-lane group per elem; wave-own elems)
        {
            int e = wh * 16 + wq * 4 + kg;
            const u16* eb = frL4 + e * 328;
            int best = 49;
            #pragma unroll
            for (int q2 = 0; q2 < 4; ++q2) {
                int cell = col + q2 * 16;
                if (cell < 49) {
                    int y = cell / 7, x = cell - y * 7;
                    u16 v = eb[(y + 1) * 36 + (x + 1) * 4];
                    if (v == (u16)0x4120 && cell < best) best = cell;  // bf16(10.0)
                }
            }
            best = min(best, __shfl_xor(best, 1, 64));
            best = min(best, __shfl_xor(best, 2, 64));
            best = min(best, __shfl_xor(best, 4, 64));
            best = min(best, __shfl_xor(best, 8, 64));
            if (col == 0) {
                float dd = 0.f, py = 0.5f, px = 0.5f;
                if (best < 49) {
                    int y = best / 7, x = best - y * 7;
                    u16 c2 = eb[(y + 1) * 36 + (x + 1) * 4 + 2];
                    dd = (float)(((int)bf2f(c2)) & 3);
                    py = (float)y / 6.0f;
                    px = (float)x / 6.0f;
                }
                fdirL[e] = make_float4(dd, py, px, 0.f);
            }
        }
        // -- B: conv2+relu+pool on the SAME wave's elems (e = wave-own).
        bf16x8 bfrag[2][2];
        #pragma unroll
        for (int s = 0; s < 2; ++s)
            #pragma unroll
            for (int nt = 0; nt < 2; ++nt)
                bfrag[s][nt] = *(const bf16x8*)(w2r + (nt * 16 + col) * 64 + s * 32 + kg * 8);
        float bias2[2] = { b2[col], b2[16 + col] };
        int oy2 = col >> 2, ox2 = col & 3;
        int aoff[2]; bool aok[2];
        #pragma unroll
        for (int s = 0; s < 2; ++s) {
            int tap = 2 * s + (kg >> 1);
            int ky = tap >> 1, kx = tap & 1;
            int iy = oy2 - 1 + ky, ix = ox2 - 1 + kx;
            aok[s] = (iy >= 0 && ix >= 0);
            aoff[s] = (iy * 4 + ix) * 16 + (kg & 1) * 8;
        }
        #pragma unroll
        for (int q = 0; q < 4; ++q) {
            int e = wh * 16 + wq * 4 + q;
            const u16* pbase = p1L + e * 256;
            bf16x8 a0 = {0,0,0,0,0,0,0,0}, a1 = {0,0,0,0,0,0,0,0};
            if (aok[0]) a0 = *(const bf16x8*)(pbase + aoff[0]);
            if (aok[1]) a1 = *(const bf16x8*)(pbase + aoff[1]);
            f32x4 acc0 = {0.f,0.f,0.f,0.f}, acc1 = {0.f,0.f,0.f,0.f};
            acc0 = __builtin_amdgcn_mfma_f32_16x16x32_bf16(a0, bfrag[0][0], acc0, 0, 0, 0);
            acc1 = __builtin_amdgcn_mfma_f32_16x16x32_bf16(a0, bfrag[0][1], acc1, 0, 0, 0);
            acc0 = __builtin_amdgcn_mfma_f32_16x16x32_bf16(a1, bfrag[1][0], acc0, 0, 0, 0);
            acc1 = __builtin_amdgcn_mfma_f32_16x16x32_bf16(a1, bfrag[1][1], acc1, 0, 0, 0);
            #pragma unroll
            for (int nt = 0; nt < 2; ++nt) {
                f32x4 acc = nt ? acc1 : acc0;
                float b = bias2[nt];
                float m0 = fmaxf(fmaxf(acc[0] + b, 0.f), fmaxf(acc[1] + b, 0.f));
                float m1 = fmaxf(fmaxf(acc[2] + b, 0.f), fmaxf(acc[3] + b, 0.f));
                float p0 = fmaxf(m0, __shfl_xor(m0, 16, 64));
                float p1 = fmaxf(m1, __shfl_xor(m1, 16, 64));
                if ((kg & 1) == 0) {
                    int qq = (kg >> 1) * 2;
                    u16* op = p2L + e * 128 + nt * 16 + col;
                    op[qq * 32]       = f2bf(p0);
                    op[(qq + 1) * 32] = f2bf(p1);
                }
            }
        }
    }
    __syncthreads();   // p2L published for C; p1L/frL4 dead; featL writable

    int colhi = col >> 3, collo = col & 7;
    // ---- phase C: conv3 (18 tiles; 2/wave + extra for wv<2) ----
    {
        bf16x8 bfrag[4][4];
        #pragma unroll
        for (int s = 0; s < 4; ++s)
            #pragma unroll
            for (int nt = 0; nt < 4; ++nt)
                bfrag[s][nt] = *(const bf16x8*)(w3r + (nt * 16 + col) * 128 + s * 32 + kg * 8);
        float bias[4];
        #pragma unroll
        for (int nt = 0; nt < 4; ++nt) bias[nt] = b3[nt * 16 + col];

        auto do_tile = [&](int i) {
            int m0 = i * 16;
            int m = m0 + col;
            u32 elem = (u32)(((unsigned long long)(u32)m * 954437177ull) >> 33); // m/9
            int p = m - (int)elem * 9;
            int oy = (p * 86) >> 8;
            int ox = p - 3 * oy;
            const u16* pbase = p2L + elem * 128 + kg * 8;
            f32x4 acc[4];
            #pragma unroll
            for (int nt = 0; nt < 4; ++nt) {
                acc[nt][0] = 0.f; acc[nt][1] = 0.f; acc[nt][2] = 0.f; acc[nt][3] = 0.f;
            }
            #pragma unroll
            for (int s = 0; s < 4; ++s) {
                int ky = s >> 1, kx = s & 1;
                int iy = oy - 1 + ky, ix = ox - 1 + kx;
                bf16x8 a = {0,0,0,0,0,0,0,0};
                if (iy >= 0 && iy <= 1 && ix >= 0 && ix <= 1)
                    a = *(const bf16x8*)(pbase + (iy * 2 + ix) * 32);
                #pragma unroll
                for (int nt = 0; nt < 4; ++nt)
                    acc[nt] = __builtin_amdgcn_mfma_f32_16x16x32_bf16(a, bfrag[s][nt], acc[nt], 0, 0, 0);
            }
            #pragma unroll
            for (int r = 0; r < 4; ++r) {
                int mr = m0 + kg * 4 + r;
                u32 er = (u32)(((unsigned long long)(u32)mr * 954437177ull) >> 33);
                int pr = mr - (int)er * 9;
                u16* fb = featL + er * 584 + collo;
                #pragma unroll
                for (int nt = 0; nt < 4; ++nt) {
                    int blk = pr * 8 + nt * 2 + colhi;
                    fb[blk * 8] = f2bf(fmaxf(acc[nt][r] + bias[nt], 0.f));
                }
            }
        };
        do_tile(wv);
        do_tile(8 + wv);
        if (wv < 2) do_tile(16 + wv);
    }
    if (t < 32) {      // carried features at k=576,577; 578..583 zeroed
        int g = b0 + (t >> 4) * BATCH + (t & 15);
        union { u16 s[8]; uint4 q; } b;
        b.s[0] = f2bf((float)ccol[g]);
        b.s[1] = f2bf((float)cobj[g]);
        #pragma unroll
        for (int i = 2; i < 8; ++i) b.s[i] = 0;
        *(uint4*)(featL + t * 584 + 576) = b.q;
    }
    __syncthreads();

    // ---- phase D: proj; wave = (row-half rh, n-tile nf); NO mid barrier --
    {
        int rh = wv & 1, nf = wv >> 1;
        const u16* arowb = featL + (rh * 16 + col) * 584;
        const u16* brow  = pwT + (nf * 16 + col) * 608 + kg * 8;
        f32x4 accA = {0.f,0.f,0.f,0.f}, accB = {0.f,0.f,0.f,0.f};
        #pragma unroll
        for (int k0 = 0; k0 < 608; k0 += 32) {
            bf16x8 a;
            if (k0 + kg * 8 < 584) {
                a = *(const bf16x8*)(arowb + k0 + kg * 8);
            } else {
                #pragma unroll
                for (int j = 0; j < 8; ++j) a[j] = 0;
            }
            bf16x8 b = *(const bf16x8*)(brow + k0);
            if ((k0 >> 5) & 1)
                accB = __builtin_amdgcn_mfma_f32_16x16x32_bf16(a, b, accB, 0, 0, 0);
            else
                accA = __builtin_amdgcn_mfma_f32_16x16x32_bf16(a, b, accA, 0, 0, 0);
        }
        // comb [0,4224) disjoint from featL [4352,23040): write immediately.
        if (t < 16) {      // dir/pos features -> comb[128..131] (hi+lo), packed
            float4 f0 = fdirL[t];
            float4 f1 = fdirL[16 + t];
            int delta = (((int)f1.x) - ((int)f0.x) + 4) & 3;
            const float ANG = (float)(2.0 * 3.14159 / 4.0);
            float ang = (float)delta * ANG;
            float x0 = sinf(ang), x1 = cosf(ang);
            float x2 = f1.y - f0.y, x3 = f1.z - f0.z;
            u32 h01 = f2bf2(x0, x1), h23 = f2bf2(x2, x3);
            *(u32*)(combHi + t * 132 + 128) = h01;
            *(u32*)(combHi + t * 132 + 130) = h23;
            float r0 = x0 - bf2f((u16)h01), r1 = x1 - bf2f((u16)(h01 >> 16));
            float r2 = x2 - bf2f((u16)h23), r3 = x3 - bf2f((u16)(h23 >> 16));
            *(u32*)(combLo + t * 132 + 128) = f2bf2(r0, r1);
            *(u32*)(combLo + t * 132 + 130) = f2bf2(r2, r3);
        }
        {
            int n = nf * 16 + col;
            float pbv = pb[n];
            #pragma unroll
            for (int r = 0; r < 4; ++r) {
                float v = fmaxf(accA[r] + accB[r] + pbv, 0.f);
                u16 hi = f2bf(v);
                int off = (kg * 4 + r) * 132 + rh * 64 + n;
                combHi[off] = hi;
                combLo[off] = f2bf(v - bf2f(hi));
            }
        }
    }
    __syncthreads();

    // ---- phase E: h1 GEMM (M=16, pre-split A, stride 132); 1 n-tile/wave -
    // s=4 over-reads (k>=132) hit stale finite bf16; h1hi/h1lo are zero
    // there -> contributes exact zeros.
    {
        const u16* ah = combHi + col * 132 + kg * 8;
        const u16* al = combLo + col * 132 + kg * 8;
        int n = wv * 16 + col;
        const u16* bh = h1hi + n * 160 + kg * 8;
        const u16* bl = h1lo + n * 160 + kg * 8;
        f32x4 accP = {0.f,0.f,0.f,0.f}, accQ = {0.f,0.f,0.f,0.f};
        #pragma unroll
        for (int s = 0; s < 5; ++s) {
            bf16x8 Ah = *(const bf16x8*)(ah + s * 32);
            bf16x8 Al = *(const bf16x8*)(al + s * 32);
            bf16x8 Bh = *(const bf16x8*)(bh + s * 32);
            bf16x8 Bl = *(const bf16x8*)(bl + s * 32);
            accP = __builtin_amdgcn_mfma_f32_16x16x32_bf16(Ah, Bh, accP, 0, 0, 0);
            accQ = __builtin_amdgcn_mfma_f32_16x16x32_bf16(Al, Bh, accQ, 0, 0, 0);
            accQ = __builtin_amdgcn_mfma_f32_16x16x32_bf16(Ah, Bl, accQ, 0, 0, 0);
        }
        float bv = h1b[n];
        #pragma unroll
        for (int r = 0; r < 4; ++r)
            hL[(kg * 4 + r) * 132 + n] = accP[r] + accQ[r] + bv;
    }
    __syncthreads();

    // ---- phase F: LN + relu; packed cvt_pk hi/lo for h2 (2 rows/wave) ----
    #pragma unroll
    for (int rr = 0; rr < 2; ++rr) {
        int row = wv * 2 + rr;
        float* rp = hL + row * 132 + l * 2;
        float2 v = *(const float2*)rp;
        float s = v.x + v.y;
        s += __shfl_xor(s, 1, 64);
        s += __shfl_xor(s, 2, 64);
        s += __shfl_xor(s, 4, 64);
        s += __shfl_xor(s, 8, 64);
        s += __shfl_xor(s, 16, 64);
        s += __shfl_xor(s, 32, 64);
        float mu = s * (1.0f / 128.0f);
        float d0 = v.x - mu, d1 = v.y - mu;
        float vs = d0 * d0 + d1 * d1;
        vs += __shfl_xor(vs, 1, 64);
        vs += __shfl_xor(vs, 2, 64);
        vs += __shfl_xor(vs, 4, 64);
        vs += __shfl_xor(vs, 8, 64);
        vs += __shfl_xor(vs, 16, 64);
        vs += __shfl_xor(vs, 32, 64);
        float rs = rsqrtf(vs * (1.0f / 128.0f) + 1e-5f);
        float o0 = fmaxf(d0 * rs * lng[l * 2]     + lnb[l * 2],     0.f);
        float o1 = fmaxf(d1 * rs * lng[l * 2 + 1] + lnb[l * 2 + 1], 0.f);
        u32 hp = f2bf2(o0, o1);
        *(u32*)(hLhi + row * 168 + l * 2) = hp;
        float r0 = o0 - bf2f((u16)hp), r1 = o1 - bf2f((u16)(hp >> 16));
        *(u32*)(hLlo + row * 168 + l * 2) = f2bf2(r0, r1);
    }
    __syncthreads();

    // ---- phase G: h2 GEMM (pre-split A, disjoint output: no inner barrier) -
    {
        const u16* ah = hLhi + col * 168 + kg * 8;
        const u16* al = hLlo + col * 168 + kg * 8;
        int n = wv * 16 + col;
        const u16* bh = h2hi + n * 128 + kg * 8;
        const u16* bl = h2lo + n * 128 + kg * 8;
        f32x4 accP = {0.f,0.f,0.f,0.f}, accQ = {0.f,0.f,0.f,0.f};
        #pragma unroll
        for (int s = 0; s < 4; ++s) {
            bf16x8 Ah = *(const bf16x8*)(ah + s * 32);
            bf16x8 Al = *(const bf16x8*)(al + s * 32);
            bf16x8 Bh = *(const bf16x8*)(bh + s * 32);
            bf16x8 Bl = *(const bf16x8*)(bl + s * 32);
            accP = __builtin_amdgcn_mfma_f32_16x16x32_bf16(Ah, Bh, accP, 0, 0, 0);
            accQ = __builtin_amdgcn_mfma_f32_16x16x32_bf16(Al, Bh, accQ, 0, 0, 0);
            accQ = __builtin_amdgcn_mfma_f32_16x16x32_bf16(Ah, Bl, accQ, 0, 0, 0);
        }
        float bv = h2b[n];
        #pragma unroll
        for (int r = 0; r < 4; ++r)
            hL[(kg * 4 + r) * 132 + n] = fmaxf(accP[r] + accQ[r] + bv, 0.f);
    }
    __syncthreads();

    // ---- phase H: h3; 4 lanes/output, stride-4-word interleave ----
    if (t < 448) {
        int oi = t >> 2, part = t & 3;       // oi: 0..111
        int row = oi / 7, j = oi - row * 7;
        const float* rp  = hL + row * 132 + part * 4;
        const float* wr0 = h3w + j * 128 + part * 4;
        float a0 = 0.f;
        #pragma unroll
        for (int cc = 0; cc < 8; ++cc) {
            float4 v = *(const float4*)(rp + cc * 16);
            float4 w = *(const float4*)(wr0 + cc * 16);
            a0 += v.x * w.x + v.y * w.y + v.z * w.z + v.w * w.w;
        }
        a0 += __shfl_xor(a0, 1, 64);
        a0 += __shfl_xor(a0, 2, 64);
        if (part == 0) out[(size_t)(b0 + row) * 7 + j] = a0 + h3b[j];
    }
}

extern "C" void kernel_launch(void* const* d_in, const int* in_sizes, int n_in,
                              void* d_out, int out_size, void* d_ws, size_t ws_size,
                              hipStream_t stream) {
    const int*   frame = (const int*)d_in[0];
    const int*   ccol  = (const int*)d_in[1];
    const int*   cobj  = (const int*)d_in[2];
    const float* w1    = (const float*)d_in[3];
    const float* b1    = (const float*)d_in[4];
    const float* w2    = (const float*)d_in[5];
    const float* b2    = (const float*)d_in[6];
    const float* w3    = (const float*)d_in[7];
    const float* b3    = (const float*)d_in[8];
    const float* pw    = (const float*)d_in[9];
    const float* pb    = (const float*)d_in[10];
    const float* h1w   = (const float*)d_in[11];
    const float* h1b   = (const float*)d_in[12];
    const float* lng   = (const float*)d_in[13];
    const float* lnb   = (const float*)d_in[14];
    const float* h2w   = (const float*)d_in[15];
    const float* h2b   = (const float*)d_in[16];
    const float* h3w   = (const float*)d_in[17];
    const float* h3b   = (const float*)d_in[18];
    float* out = (float*)d_out;

    char* ws = (char*)d_ws;
    u16*   pwT      = (u16*)(ws + 0);                    // 77824 B
    u16*   w2r      = (u16*)(ws + 131072);               // 4096 B
    u16*   w3r      = (u16*)(ws + 139264);               // 16384 B
    u16*   h2hi     = (u16*)(ws + 163840);               // 32768 B
    u16*   h2lo     = (u16*)(ws + 196608);               // 32768 B
    u16*   h1hi     = (u16*)(ws + 229376);               // 40960 B
    u16*   h1lo     = (u16*)(ws + 270336);               // 40960 B
    u16*   w1hi     = (u16*)(ws + 311296);               // 1024 B
    u16*   w1lo     = (u16*)(ws + 312320);               // 1024 B

    k0_prep<<<340, 256, 0, stream>>>(pw, w2, w3, h2w, h1w, w1,
                                     pwT, w2r, w3r, h2hi, h2lo, h1hi, h1lo,
                                     w1hi, w1lo);
    kall<<<2048, 512, 0, stream>>>(frame, w1hi, w1lo, b1, w2r, b2,
                                   w3r, b3, ccol, cobj, pwT, pb,
                                   h1hi, h1lo, h1b, lng, lnb,
                                   h2hi, h2lo, h2b, h3w, h3b, out);
}

// Round 22
// 212.010 us; speedup vs baseline: 1.0653x; 1.0653x over previous
//
#include <hip/hip_runtime.h>
#include <hip/hip_bf16.h>

#define BATCH 32768

typedef unsigned short u16;
typedef unsigned int u32;
typedef __attribute__((ext_vector_type(8))) short bf16x8;
typedef __attribute__((ext_vector_type(4))) float f32x4;

__device__ __forceinline__ float bf2f(u16 u) {
    union { u32 u; float f; } c; c.u = ((u32)u) << 16; return c.f;
}
// HW bf16 conversion (RNE), gfx950 v_cvt_pk_bf16_f32: 1 VALU for 2 floats.
__device__ __forceinline__ u16 f2bf(float f) {
    u32 r;
    asm("v_cvt_pk_bf16_f32 %0, %1, %1" : "=v"(r) : "v"(f));
    return (u16)r;
}
__device__ __forceinline__ u32 f2bf2(float lo, float hi) {  // [bf(lo) | bf(hi)<<16]
    u32 r;
    asm("v_cvt_pk_bf16_f32 %0, %1, %2" : "=v"(r) : "v"(lo), "v"(hi));
    return r;
}
__device__ __forceinline__ u16 i2bf(int v) {   // exact for small non-neg ints
    union { float f; u32 u; } c; c.f = (float)v;
    return (u16)(c.u >> 16);
}

// ---------------- K0: weight prep (R9 layouts) ---------------------------
__global__ __launch_bounds__(256) void k0_prep(const float* __restrict__ pw,
        const float* __restrict__ w2, const float* __restrict__ w3,
        const float* __restrict__ h2w, const float* __restrict__ h1w,
        const float* __restrict__ w1,
        u16* __restrict__ pwT, u16* __restrict__ w2r, u16* __restrict__ w3r,
        u16* __restrict__ h2hi, u16* __restrict__ h2lo,
        u16* __restrict__ h1hi, u16* __restrict__ h1lo,
        u16* __restrict__ w1hi, u16* __restrict__ w1lo) {
    int idx = blockIdx.x * 256 + threadIdx.x;
    if (idx < 38912) {
        int j = idx / 608, kk = idx - j * 608;
        float v = 0.f;
        if (kk < 576) {
            int p = kk >> 6, oc = kk & 63;
            v = pw[j * 578 + oc * 9 + p];
        } else if (kk < 578) {
            v = pw[j * 578 + kk];
        }
        pwT[idx] = f2bf(v);
    } else if (idx < 40960) {
        int i = idx - 38912;
        int oc = i >> 6, rem = i & 63, tap = rem >> 4, ic = rem & 15;
        w2r[i] = f2bf(w2[oc * 64 + ic * 4 + tap]);
    } else if (idx < 49152) {
        int i = idx - 40960;
        int oc = i >> 7, rem = i & 127, tap = rem >> 5, ic = rem & 31;
        w3r[i] = f2bf(w3[oc * 128 + ic * 4 + tap]);
    } else if (idx < 65536) {
        int i = idx - 49152;
        float v = h2w[i];
        u16 hi = f2bf(v);
        h2hi[i] = hi;
        h2lo[i] = f2bf(v - bf2f(hi));
    } else if (idx < 86016) {
        int i = idx - 65536;
        int j = i / 160, k = i - j * 160;
        float v = (k < 132) ? h1w[j * 132 + k] : 0.f;
        u16 hi = f2bf(v);
        h1hi[i] = hi;
        h1lo[i] = f2bf(v - bf2f(hi));
    } else if (idx < 86528) {
        int i = idx - 86016;               // [oc16][k32], k = ky*8+kx*4+c
        int oc = i >> 5, k = i & 31;
        int ky = k >> 3, kx = (k >> 2) & 1, c = k & 3;
        float v = (ky < 2 && c < 3) ? w1[oc * 12 + c * 4 + ky * 2 + kx] : 0.f;
        u16 hi = f2bf(v);
        w1hi[i] = hi;
        w1lo[i] = f2bf(v - bf2f(hi));
    }
}

// ---------------- KALL: whole network, 1 block = 16 pairs, 512 threads ---
// R22 = R21 with comb stride 132 -> 136 u16. R21 post-mortem: stride 132
// (264 B) broke 16-B alignment of phase E's ds_read_b128 A-reads (R19's
// 168 = 336 B was aligned); misaligned b128 splits cost ~14 us. 136 u16 =
// 272 B = 17x16 (aligned); 68 words = 4 mod 32 -> col pairs overlap
// exactly -> 2-way bank alias = free. comb [0,4352) abuts featL at 4352:
// disjoint -> mid-D barrier stays removed. E s=4 over-reads hit stale
// finite bf16 x zero-padded B = exact zeros (unchanged mechanism).
__global__ __launch_bounds__(512, 4) void kall(const int* __restrict__ frame,
        const u16* __restrict__ w1hi, const u16* __restrict__ w1lo,
        const float* __restrict__ b1,
        const u16* __restrict__ w2r, const float* __restrict__ b2,
        const u16* __restrict__ w3r, const float* __restrict__ b3,
        const int* __restrict__ ccol, const int* __restrict__ cobj,
        const u16* __restrict__ pwT, const float* __restrict__ pb,
        const u16* __restrict__ h1hi, const u16* __restrict__ h1lo,
        const float* __restrict__ h1b,
        const float* __restrict__ lng, const float* __restrict__ lnb,
        const u16* __restrict__ h2hi, const u16* __restrict__ h2lo,
        const float* __restrict__ h2b,
        const float* __restrict__ h3w, const float* __restrict__ h3b,
        float* __restrict__ out) {
    __shared__ u16 lds[23040];     // 46080 B
    __shared__ float4 fdirL[32];   // 512 B
    u16* p2L    = lds;             // [0,4096)      32 x 128
    u16* p1L    = lds + 4096;      // [4096,12288)  32 x 256
    u16* frL4   = lds + 12288;     // [12288,22784) 32 x 328 (4-ch, both h)
    u16* featL  = lds + 4352;      // [4352,23040)  32 x 584 (overlay after B)
    u16* combHi = lds;             // [0,2176)      16 x 136
    u16* combLo = lds + 2176;      // [2176,4352)
    float* hL   = (float*)(lds + 5376);  // [5376,9600) 16 x 132 f32
    u16* hLhi   = lds + 9600;      // [9600,12288)  16 x 168
    u16* hLlo   = lds + 12288;     // [12288,14976)

    int t = threadIdx.x;
    int l = t & 63;
    int wv = t >> 6;               // 0..7
    int col = l & 15;
    int kg = l >> 4;
    int wq = wv & 3, wh = wv >> 2;
    int b0 = blockIdx.x * 16;

    // halo-only zero (rows 0/8, cols 0/8, pad: 33 uint2/elem, disjoint from
    // loader interior writes -> NO barrier between zero and load)
    #pragma unroll
    for (int i = 0; i < 3; ++i) {
        int idx = i * 512 + t;
        if (idx < 1056) {
            int le = idx / 33, h = idx - le * 33;
            int off;
            if (h < 9) off = h * 4;                       // row 0
            else if (h < 18) off = 288 + (h - 9) * 4;     // row 8
            else if (h < 25) off = (h - 17) * 36;         // col 0, rows 1-7
            else if (h < 32) off = (h - 24) * 36 + 32;    // col 8, rows 1-7
            else off = 324;                               // elem pad
            *(uint2*)(frL4 + le * 328 + off) = make_uint2(0u, 0u);
        }
    }
    // cell loader: 1 thread = 1 pixel (3 ints -> packed 4ch uint2)
    #pragma unroll
    for (int i = 0; i < 4; ++i) {
        int c = i * 512 + t;
        if (c < 1568) {
            int le = c / 49, rem = c - le * 49;
            int y = rem / 7, x = rem - y * 7;
            const int* fp = frame
                + ((size_t)b0 + (size_t)(le & 15) + (size_t)(le >> 4) * BATCH) * 147
                + rem * 3;
            int v0 = fp[0], v1 = fp[1], v2 = fp[2];
            uint2 st;
            st.x = (u32)i2bf(v0) | ((u32)i2bf(v1) << 16);
            st.y = (u32)i2bf(v2);                          // ch3 = 0
            *(uint2*)(frL4 + le * 328 + (y + 1) * 36 + (x + 1) * 4) = st;
        }
    }
    __syncthreads();

    // ---- phase A+B fused: conv1+pool -> (same-wave) conv2+pool ----------
    {
        // -- A: conv1+relu+pool (2 MFMA hi/lo, kg<2 loads), wave-own elems --
        bf16x8 c1hi = *(const bf16x8*)(w1hi + col * 32 + kg * 8);
        bf16x8 c1lo = *(const bf16x8*)(w1lo + col * 32 + kg * 8);
        float c1b = b1[col];
        bool wr1 = (kg < 2);
        #pragma unroll
        for (int q = 0; q < 4; ++q) {
            int le = wh * 16 + wq * 4 + q;
            const u16* eb = frL4 + le * 328;
            u16* op = p1L + le * 256;
            #pragma unroll
            for (int mt = 0; mt < 4; ++mt) {
                int posA = mt * 16 + col;
                int oy = posA >> 3, ox = posA & 7;
                bf16x8 a;
                if (kg < 2) {      // K-slice kg = row ky; 2 pixels x 4ch
                    const u16* ap = eb + (oy + kg) * 36 + ox * 4;
                    union { uint2 d[2]; bf16x8 v; } uu;
                    uu.d[0] = *(const uint2*)ap;
                    uu.d[1] = *(const uint2*)(ap + 4);
                    a = uu.v;
                } else {
                    #pragma unroll
                    for (int j = 0; j < 8; ++j) a[j] = 0;
                }
                f32x4 acc = {0.f, 0.f, 0.f, 0.f};
                acc = __builtin_amdgcn_mfma_f32_16x16x32_bf16(a, c1hi, acc, 0, 0, 0);
                acc = __builtin_amdgcn_mfma_f32_16x16x32_bf16(a, c1lo, acc, 0, 0, 0);
                float x0 = fmaxf(acc[0] + c1b, 0.f);
                float x1 = fmaxf(acc[1] + c1b, 0.f);
                float x2 = fmaxf(acc[2] + c1b, 0.f);
                float x3 = fmaxf(acc[3] + c1b, 0.f);
                float y0 = fmaxf(x0, x1);
                float y1 = fmaxf(x2, x3);
                float m0 = fmaxf(y0, __shfl_xor(y0, 32, 64));
                float m1 = fmaxf(y1, __shfl_xor(y1, 32, 64));
                if (wr1) {
                    op[(mt * 4 + kg * 2 + 0) * 16 + col] = f2bf(m0);
                    op[(mt * 4 + kg * 2 + 1) * 16 + col] = f2bf(m1);
                }
            }
        }
        // dir/pos scan (16-lane group per elem; wave-own elems)
        {
            int e = wh * 16 + wq * 4 + kg;
            const u16* eb = frL4 + e * 328;
            int best = 49;
            #pragma unroll
            for (int q2 = 0; q2 < 4; ++q2) {
                int cell = col + q2 * 16;
                if (cell < 49) {
                    int y = cell / 7, x = cell - y * 7;
                    u16 v = eb[(y + 1) * 36 + (x + 1) * 4];
                    if (v == (u16)0x4120 && cell < best) best = cell;  // bf16(10.0)
                }
            }
            best = min(best, __shfl_xor(best, 1, 64));
            best = min(best, __shfl_xor(best, 2, 64));
            best = min(best, __shfl_xor(best, 4, 64));
            best = min(best, __shfl_xor(best, 8, 64));
            if (col == 0) {
                float dd = 0.f, py = 0.5f, px = 0.5f;
                if (best < 49) {
                    int y = best / 7, x = best - y * 7;
                    u16 c2 = eb[(y + 1) * 36 + (x + 1) * 4 + 2];
                    dd = (float)(((int)bf2f(c2)) & 3);
                    py = (float)y / 6.0f;
                    px = (float)x / 6.0f;
                }
                fdirL[e] = make_float4(dd, py, px, 0.f);
            }
        }
        // -- B: conv2+relu+pool on the SAME wave's elems (e = wave-own).
        bf16x8 bfrag[2][2];
        #pragma unroll
        for (int s = 0; s < 2; ++s)
            #pragma unroll
            for (int nt = 0; nt < 2; ++nt)
                bfrag[s][nt] = *(const bf16x8*)(w2r + (nt * 16 + col) * 64 + s * 32 + kg * 8);
        float bias2[2] = { b2[col], b2[16 + col] };
        int oy2 = col >> 2, ox2 = col & 3;
        int aoff[2]; bool aok[2];
        #pragma unroll
        for (int s = 0; s < 2; ++s) {
            int tap = 2 * s + (kg >> 1);
            int ky = tap >> 1, kx = tap & 1;
            int iy = oy2 - 1 + ky, ix = ox2 - 1 + kx;
            aok[s] = (iy >= 0 && ix >= 0);
            aoff[s] = (iy * 4 + ix) * 16 + (kg & 1) * 8;
        }
        #pragma unroll
        for (int q = 0; q < 4; ++q) {
            int e = wh * 16 + wq * 4 + q;
            const u16* pbase = p1L + e * 256;
            bf16x8 a0 = {0,0,0,0,0,0,0,0}, a1 = {0,0,0,0,0,0,0,0};
            if (aok[0]) a0 = *(const bf16x8*)(pbase + aoff[0]);
            if (aok[1]) a1 = *(const bf16x8*)(pbase + aoff[1]);
            f32x4 acc0 = {0.f,0.f,0.f,0.f}, acc1 = {0.f,0.f,0.f,0.f};
            acc0 = __builtin_amdgcn_mfma_f32_16x16x32_bf16(a0, bfrag[0][0], acc0, 0, 0, 0);
            acc1 = __builtin_amdgcn_mfma_f32_16x16x32_bf16(a0, bfrag[0][1], acc1, 0, 0, 0);
            acc0 = __builtin_amdgcn_mfma_f32_16x16x32_bf16(a1, bfrag[1][0], acc0, 0, 0, 0);
            acc1 = __builtin_amdgcn_mfma_f32_16x16x32_bf16(a1, bfrag[1][1], acc1, 0, 0, 0);
            #pragma unroll
            for (int nt = 0; nt < 2; ++nt) {
                f32x4 acc = nt ? acc1 : acc0;
                float b = bias2[nt];
                float m0 = fmaxf(fmaxf(acc[0] + b, 0.f), fmaxf(acc[1] + b, 0.f));
                float m1 = fmaxf(fmaxf(acc[2] + b, 0.f), fmaxf(acc[3] + b, 0.f));
                float p0 = fmaxf(m0, __shfl_xor(m0, 16, 64));
                float p1 = fmaxf(m1, __shfl_xor(m1, 16, 64));
                if ((kg & 1) == 0) {
                    int qq = (kg >> 1) * 2;
                    u16* op = p2L + e * 128 + nt * 16 + col;
                    op[qq * 32]       = f2bf(p0);
                    op[(qq + 1) * 32] = f2bf(p1);
                }
            }
        }
    }
    __syncthreads();   // p2L published for C; p1L/frL4 dead; featL writable

    int colhi = col >> 3, collo = col & 7;
    // ---- phase C: conv3 (18 tiles; 2/wave + extra for wv<2) ----
    {
        bf16x8 bfrag[4][4];
        #pragma unroll
        for (int s = 0; s < 4; ++s)
            #pragma unroll
            for (int nt = 0; nt < 4; ++nt)
                bfrag[s][nt] = *(const bf16x8*)(w3r + (nt * 16 + col) * 128 + s * 32 + kg * 8);
        float bias[4];
        #pragma unroll
        for (int nt = 0; nt < 4; ++nt) bias[nt] = b3[nt * 16 + col];

        auto do_tile = [&](int i) {
            int m0 = i * 16;
            int m = m0 + col;
            u32 elem = (u32)(((unsigned long long)(u32)m * 954437177ull) >> 33); // m/9
            int p = m - (int)elem * 9;
            int oy = (p * 86) >> 8;
            int ox = p - 3 * oy;
            const u16* pbase = p2L + elem * 128 + kg * 8;
            f32x4 acc[4];
            #pragma unroll
            for (int nt = 0; nt < 4; ++nt) {
                acc[nt][0] = 0.f; acc[nt][1] = 0.f; acc[nt][2] = 0.f; acc[nt][3] = 0.f;
            }
            #pragma unroll
            for (int s = 0; s < 4; ++s) {
                int ky = s >> 1, kx = s & 1;
                int iy = oy - 1 + ky, ix = ox - 1 + kx;
                bf16x8 a = {0,0,0,0,0,0,0,0};
                if (iy >= 0 && iy <= 1 && ix >= 0 && ix <= 1)
                    a = *(const bf16x8*)(pbase + (iy * 2 + ix) * 32);
                #pragma unroll
                for (int nt = 0; nt < 4; ++nt)
                    acc[nt] = __builtin_amdgcn_mfma_f32_16x16x32_bf16(a, bfrag[s][nt], acc[nt], 0, 0, 0);
            }
            #pragma unroll
            for (int r = 0; r < 4; ++r) {
                int mr = m0 + kg * 4 + r;
                u32 er = (u32)(((unsigned long long)(u32)mr * 954437177ull) >> 33);
                int pr = mr - (int)er * 9;
                u16* fb = featL + er * 584 + collo;
                #pragma unroll
                for (int nt = 0; nt < 4; ++nt) {
                    int blk = pr * 8 + nt * 2 + colhi;
                    fb[blk * 8] = f2bf(fmaxf(acc[nt][r] + bias[nt], 0.f));
                }
            }
        };
        do_tile(wv);
        do_tile(8 + wv);
        if (wv < 2) do_tile(16 + wv);
    }
    if (t < 32) {      // carried features at k=576,577; 578..583 zeroed
        int g = b0 + (t >> 4) * BATCH + (t & 15);
        union { u16 s[8]; uint4 q; } b;
        b.s[0] = f2bf((float)ccol[g]);
        b.s[1] = f2bf((float)cobj[g]);
        #pragma unroll
        for (int i = 2; i < 8; ++i) b.s[i] = 0;
        *(uint4*)(featL + t * 584 + 576) = b.q;
    }
    __syncthreads();

    // ---- phase D: proj; wave = (row-half rh, n-tile nf); NO mid barrier --
    {
        int rh = wv & 1, nf = wv >> 1;
        const u16* arowb = featL + (rh * 16 + col) * 584;
        const u16* brow  = pwT + (nf * 16 + col) * 608 + kg * 8;
        f32x4 accA = {0.f,0.f,0.f,0.f}, accB = {0.f,0.f,0.f,0.f};
        #pragma unroll
        for (int k0 = 0; k0 < 608; k0 += 32) {
            bf16x8 a;
            if (k0 + kg * 8 < 584) {
                a = *(const bf16x8*)(arowb + k0 + kg * 8);
            } else {
                #pragma unroll
                for (int j = 0; j < 8; ++j) a[j] = 0;
            }
            bf16x8 b = *(const bf16x8*)(brow + k0);
            if ((k0 >> 5) & 1)
                accB = __builtin_amdgcn_mfma_f32_16x16x32_bf16(a, b, accB, 0, 0, 0);
            else
                accA = __builtin_amdgcn_mfma_f32_16x16x32_bf16(a, b, accA, 0, 0, 0);
        }
        // comb [0,4352) disjoint from featL [4352,23040): write immediately.
        if (t < 16) {      // dir/pos features -> comb[128..131] (hi+lo), packed
            float4 f0 = fdirL[t];
            float4 f1 = fdirL[16 + t];
            int delta = (((int)f1.x) - ((int)f0.x) + 4) & 3;
            const float ANG = (float)(2.0 * 3.14159 / 4.0);
            float ang = (float)delta * ANG;
            float x0 = sinf(ang), x1 = cosf(ang);
            float x2 = f1.y - f0.y, x3 = f1.z - f0.z;
            u32 h01 = f2bf2(x0, x1), h23 = f2bf2(x2, x3);
            *(u32*)(combHi + t * 136 + 128) = h01;
            *(u32*)(combHi + t * 136 + 130) = h23;
            float r0 = x0 - bf2f((u16)h01), r1 = x1 - bf2f((u16)(h01 >> 16));
            float r2 = x2 - bf2f((u16)h23), r3 = x3 - bf2f((u16)(h23 >> 16));
            *(u32*)(combLo + t * 136 + 128) = f2bf2(r0, r1);
            *(u32*)(combLo + t * 136 + 130) = f2bf2(r2, r3);
        }
        {
            int n = nf * 16 + col;
            float pbv = pb[n];
            #pragma unroll
            for (int r = 0; r < 4; ++r) {
                float v = fmaxf(accA[r] + accB[r] + pbv, 0.f);
                u16 hi = f2bf(v);
                int off = (kg * 4 + r) * 136 + rh * 64 + n;
                combHi[off] = hi;
                combLo[off] = f2bf(v - bf2f(hi));
            }
        }
    }
    __syncthreads();

    // ---- phase E: h1 GEMM (M=16, pre-split A, stride 136); 1 n-tile/wave -
    // s=4 over-reads (k>=136 window) hit stale finite bf16; h1hi/h1lo are
    // zero there -> contributes exact zeros.
    {
        const u16* ah = combHi + col * 136 + kg * 8;
        const u16* al = combLo + col * 136 + kg * 8;
        int n = wv * 16 + col;
        const u16* bh = h1hi + n * 160 + kg * 8;
        const u16* bl = h1lo + n * 160 + kg * 8;
        f32x4 accP = {0.f,0.f,0.f,0.f}, accQ = {0.f,0.f,0.f,0.f};
        #pragma unroll
        for (int s = 0; s < 5; ++s) {
            bf16x8 Ah = *(const bf16x8*)(ah + s * 32);
            bf16x8 Al = *(const bf16x8*)(al + s * 32);
            bf16x8 Bh = *(const bf16x8*)(bh + s * 32);
            bf16x8 Bl = *(const bf16x8*)(bl + s * 32);
            accP = __builtin_amdgcn_mfma_f32_16x16x32_bf16(Ah, Bh, accP, 0, 0, 0);
            accQ = __builtin_amdgcn_mfma_f32_16x16x32_bf16(Al, Bh, accQ, 0, 0, 0);
            accQ = __builtin_amdgcn_mfma_f32_16x16x32_bf16(Ah, Bl, accQ, 0, 0, 0);
        }
        float bv = h1b[n];
        #pragma unroll
        for (int r = 0; r < 4; ++r)
            hL[(kg * 4 + r) * 132 + n] = accP[r] + accQ[r] + bv;
    }
    __syncthreads();

    // ---- phase F: LN + relu; packed cvt_pk hi/lo for h2 (2 rows/wave) ----
    #pragma unroll
    for (int rr = 0; rr < 2; ++rr) {
        int row = wv * 2 + rr;
        float* rp = hL + row * 132 + l * 2;
        float2 v = *(const float2*)rp;
        float s = v.x + v.y;
        s += __shfl_xor(s, 1, 64);
        s += __shfl_xor(s, 2, 64);
        s += __shfl_xor(s, 4, 64);
        s += __shfl_xor(s, 8, 64);
        s += __shfl_xor(s, 16, 64);
        s += __shfl_xor(s, 32, 64);
        float mu = s * (1.0f / 128.0f);
        float d0 = v.x - mu, d1 = v.y - mu;
        float vs = d0 * d0 + d1 * d1;
        vs += __shfl_xor(vs, 1, 64);
        vs += __shfl_xor(vs, 2, 64);
        vs += __shfl_xor(vs, 4, 64);
        vs += __shfl_xor(vs, 8, 64);
        vs += __shfl_xor(vs, 16, 64);
        vs += __shfl_xor(vs, 32, 64);
        float rs = rsqrtf(vs * (1.0f / 128.0f) + 1e-5f);
        float o0 = fmaxf(d0 * rs * lng[l * 2]     + lnb[l * 2],     0.f);
        float o1 = fmaxf(d1 * rs * lng[l * 2 + 1] + lnb[l * 2 + 1], 0.f);
        u32 hp = f2bf2(o0, o1);
        *(u32*)(hLhi + row * 168 + l * 2) = hp;
        float r0 = o0 - bf2f((u16)hp), r1 = o1 - bf2f((u16)(hp >> 16));
        *(u32*)(hLlo + row * 168 + l * 2) = f2bf2(r0, r1);
    }
    __syncthreads();

    // ---- phase G: h2 GEMM (pre-split A, disjoint output: no inner barrier) -
    {
        const u16* ah = hLhi + col * 168 + kg * 8;
        const u16* al = hLlo + col * 168 + kg * 8;
        int n = wv * 16 + col;
        const u16* bh = h2hi + n * 128 + kg * 8;
        const u16* bl = h2lo + n * 128 + kg * 8;
        f32x4 accP = {0.f,0.f,0.f,0.f}, accQ = {0.f,0.f,0.f,0.f};
        #pragma unroll
        for (int s = 0; s < 4; ++s) {
            bf16x8 Ah = *(const bf16x8*)(ah + s * 32);
            bf16x8 Al = *(const bf16x8*)(al + s * 32);
            bf16x8 Bh = *(const bf16x8*)(bh + s * 32);
            bf16x8 Bl = *(const bf16x8*)(bl + s * 32);
            accP = __builtin_amdgcn_mfma_f32_16x16x32_bf16(Ah, Bh, accP, 0, 0, 0);
            accQ = __builtin_amdgcn_mfma_f32_16x16x32_bf16(Al, Bh, accQ, 0, 0, 0);
            accQ = __builtin_amdgcn_mfma_f32_16x16x32_bf16(Ah, Bl, accQ, 0, 0, 0);
        }
        float bv = h2b[n];
        #pragma unroll
        for (int r = 0; r < 4; ++r)
            hL[(kg * 4 + r) * 132 + n] = fmaxf(accP[r] + accQ[r] + bv, 0.f);
    }
    __syncthreads();

    // ---- phase H: h3; 4 lanes/output, stride-4-word interleave ----
    if (t < 448) {
        int oi = t >> 2, part = t & 3;       // oi: 0..111
        int row = oi / 7, j = oi - row * 7;
        const float* rp  = hL + row * 132 + part * 4;
        const float* wr0 = h3w + j * 128 + part * 4;
        float a0 = 0.f;
        #pragma unroll
        for (int cc = 0; cc < 8; ++cc) {
            float4 v = *(const float4*)(rp + cc * 16);
            float4 w = *(const float4*)(wr0 + cc * 16);
            a0 += v.x * w.x + v.y * w.y + v.z * w.z + v.w * w.w;
        }
        a0 += __shfl_xor(a0, 1, 64);
        a0 += __shfl_xor(a0, 2, 64);
        if (part == 0) out[(size_t)(b0 + row) * 7 + j] = a0 + h3b[j];
    }
}

extern "C" void kernel_launch(void* const* d_in, const int* in_sizes, int n_in,
                              void* d_out, int out_size, void* d_ws, size_t ws_size,
                              hipStream_t stream) {
    const int*   frame = (const int*)d_in[0];
    const int*   ccol  = (const int*)d_in[1];
    const int*   cobj  = (const int*)d_in[2];
    const float* w1    = (const float*)d_in[3];
    const float* b1    = (const float*)d_in[4];
    const float* w2    = (const float*)d_in[5];
    const float* b2    = (const float*)d_in[6];
    const float* w3    = (const float*)d_in[7];
    const float* b3    = (const float*)d_in[8];
    const float* pw    = (const float*)d_in[9];
    const float* pb    = (const float*)d_in[10];
    const float* h1w   = (const float*)d_in[11];
    const float* h1b   = (const float*)d_in[12];
    const float* lng   = (const float*)d_in[13];
    const float* lnb   = (const float*)d_in[14];
    const float* h2w   = (const float*)d_in[15];
    const float* h2b   = (const float*)d_in[16];
    const float* h3w   = (const float*)d_in[17];
    const float* h3b   = (const float*)d_in[18];
    float* out = (float*)d_out;

    char* ws = (char*)d_ws;
    u16*   pwT      = (u16*)(ws + 0);                    // 77824 B
    u16*   w2r      = (u16*)(ws + 131072);               // 4096 B
    u16*   w3r      = (u16*)(ws + 139264);               // 16384 B
    u16*   h2hi     = (u16*)(ws + 163840);               // 32768 B
    u16*   h2lo     = (u16*)(ws + 196608);               // 32768 B
    u16*   h1hi     = (u16*)(ws + 229376);               // 40960 B
    u16*   h1lo     = (u16*)(ws + 270336);               // 40960 B
    u16*   w1hi     = (u16*)(ws + 311296);               // 1024 B
    u16*   w1lo     = (u16*)(ws + 312320);               // 1024 B

    k0_prep<<<340, 256, 0, stream>>>(pw, w2, w3, h2w, h1w, w1,
                                     pwT, w2r, w3r, h2hi, h2lo, h1hi, h1lo,
                                     w1hi, w1lo);
    kall<<<2048, 512, 0, stream>>>(frame, w1hi, w1lo, b1, w2r, b2,
                                   w3r, b3, ccol, cobj, pwT, pb,
                                   h1hi, h1lo, h1b, lng, lnb,
                                   h2hi, h2lo, h2b, h3w, h3b, out);
}